// Round 5
// baseline (408.180 us; speedup 1.0000x reference)
//
#include <hip/hip_runtime.h>
#include <math.h>

#define NN 100000
#define NE 600000
#define DIM 128
#define SEG 1024
#define NSEG 98   // ceil(100000/1024)
#define PBLK 2048 // pooled-agg grid

typedef __attribute__((ext_vector_type(8))) short short8;
typedef __attribute__((ext_vector_type(4))) float floatx4;

// bf16 helpers (RNE)
static __device__ __forceinline__ unsigned short f2bf(float f) {
    union { float f; unsigned u; } v; v.f = f;
    unsigned r = v.u + 0x7fffu + ((v.u >> 16) & 1u);
    return (unsigned short)(r >> 16);
}
static __device__ __forceinline__ float bflo(unsigned int p) {
    union { unsigned u; float f; } v; v.u = p << 16; return v.f;
}
static __device__ __forceinline__ float bfhi(unsigned int p) {
    union { unsigned u; float f; } v; v.u = p & 0xffff0000u; return v.f;
}

// ---------------- CSR build ----------------
__global__ void k_zero(int* __restrict__ counts, int n1) {
    int i = blockIdx.x * blockDim.x + threadIdx.x;
    if (i < n1) counts[i] = 0;
}

__global__ void k_count(const int* __restrict__ col, int* __restrict__ counts, int E) {
    int i = blockIdx.x * blockDim.x + threadIdx.x;
    if (i < E) atomicAdd(&counts[col[i]], 1);
}

__global__ void k_rsqrt(const int* __restrict__ counts, float* __restrict__ dinv, int n) {
    int i = blockIdx.x * blockDim.x + threadIdx.x;
    if (i < n) dinv[i] = rsqrtf((float)counts[i] + 1.0f);
}

__global__ __launch_bounds__(256) void k_scan1(int* __restrict__ data, int* __restrict__ segsum, int n) {
    __shared__ int s[256];
    const int t = threadIdx.x;
    const int base = blockIdx.x * SEG + t * 4;
    int v[4];
#pragma unroll
    for (int i = 0; i < 4; ++i) v[i] = (base + i < n) ? data[base + i] : 0;
    int tsum = v[0] + v[1] + v[2] + v[3];
    s[t] = tsum;
    __syncthreads();
    for (int off = 1; off < 256; off <<= 1) {
        int x = (t >= off) ? s[t - off] : 0;
        __syncthreads();
        s[t] += x;
        __syncthreads();
    }
    int run = s[t] - tsum;
#pragma unroll
    for (int i = 0; i < 4; ++i) {
        if (base + i < n) data[base + i] = run;
        run += v[i];
    }
    if (t == 255) segsum[blockIdx.x] = s[255];
}

__global__ void k_scan2(int* __restrict__ segsum, int* __restrict__ offsets, int n) {
    if (threadIdx.x == 0 && blockIdx.x == 0) {
        int run = 0;
        for (int i = 0; i < NSEG; ++i) { int t = segsum[i]; segsum[i] = run; run += t; }
        offsets[n] = run;
    }
}

__global__ __launch_bounds__(256) void k_scan3(int* __restrict__ offsets, const int* __restrict__ segsum,
                                               int* __restrict__ cursor, int n) {
    const int base = blockIdx.x * SEG + threadIdx.x * 4;
    const int so = segsum[blockIdx.x];
#pragma unroll
    for (int i = 0; i < 4; ++i) {
        if (base + i < n) {
            int o = offsets[base + i] + so;
            offsets[base + i] = o;
            cursor[base + i] = o;
        }
    }
}

__global__ void k_fill(const int* __restrict__ rows, const int* __restrict__ cols,
                       const float* __restrict__ dinv, int* __restrict__ cursor,
                       int2* __restrict__ adjw, int E) {
    int e = blockIdx.x * blockDim.x + threadIdx.x;
    if (e < E) {
        int r = rows[e];
        int c = cols[e];
        int pos = atomicAdd(&cursor[c], 1);
        adjw[pos] = make_int2(r, __float_as_int(dinv[r] * dinv[c]));
    }
}

// ---------------- W pack: fragment-order bf16 ----------------
__global__ void k_wpack(const float* __restrict__ W, unsigned short* __restrict__ Wp) {
    int e = blockIdx.x * 256 + threadIdx.x;   // 0..16383
    int j  = e & 7;
    int L  = (e >> 3) & 63;
    int kk = (e >> 9) & 3;
    int ct = e >> 11;
    int k = kk * 32 + (L >> 4) * 8 + j;
    int c = ct * 16 + (L & 15);
    Wp[e] = f2bf(W[k * DIM + c]);
}

// ---------------- plain MFMA GEMM (layer 0: A = fp32 x) ----------------
__global__ __launch_bounds__(256) void k_gemm0(const float* __restrict__ A,
                                               const unsigned short* __restrict__ Wp,
                                               unsigned short* __restrict__ H, int n) {
    __shared__ __align__(16) unsigned short As[64][136];
    const int t = threadIdx.x;
    const int wid = t >> 6, lane = t & 63;
    const int wy = wid & 1, wx = wid >> 1;
    const int base = blockIdx.x * 64;

    short8 Bf[4][4];
    {
        const short8* wp8 = (const short8*)Wp;
#pragma unroll
        for (int tt = 0; tt < 4; ++tt)
#pragma unroll
            for (int kk = 0; kk < 4; ++kk)
                Bf[tt][kk] = wp8[(((wx * 4 + tt) * 4 + kk) * 64) + lane];
    }

#pragma unroll
    for (int it = 0; it < 8; ++it) {
        int idx = it * 256 + t;
        int row = idx >> 5, seg = idx & 31;
        int r = base + row;
        float4 v = make_float4(0.f, 0.f, 0.f, 0.f);
        if (r < n) v = ((const float4*)(A + (size_t)r * DIM))[seg];
        ushort4 o;
        o.x = f2bf(v.x); o.y = f2bf(v.y); o.z = f2bf(v.z); o.w = f2bf(v.w);
        *((ushort4*)&As[row][seg * 4]) = o;
    }
    __syncthreads();

    floatx4 acc[2][4];
#pragma unroll
    for (int rs = 0; rs < 2; ++rs)
#pragma unroll
        for (int tt = 0; tt < 4; ++tt) acc[rs][tt] = (floatx4){0.f, 0.f, 0.f, 0.f};

    const int m = lane & 15, q = lane >> 4;
#pragma unroll
    for (int rs = 0; rs < 2; ++rs) {
        const int rbase = wy * 32 + rs * 16 + m;
        short8 Af[4];
#pragma unroll
        for (int kk = 0; kk < 4; ++kk)
            Af[kk] = *((const short8*)&As[rbase][kk * 32 + q * 8]);
#pragma unroll
        for (int kk = 0; kk < 4; ++kk)
#pragma unroll
            for (int tt = 0; tt < 4; ++tt)
                acc[rs][tt] = __builtin_amdgcn_mfma_f32_16x16x32_bf16(Af[kk], Bf[tt][kk],
                                                                     acc[rs][tt], 0, 0, 0);
    }
    __syncthreads();

#pragma unroll
    for (int rs = 0; rs < 2; ++rs)
#pragma unroll
        for (int tt = 0; tt < 4; ++tt) {
            const int col = wx * 64 + tt * 16 + m;
            const int rowb = wy * 32 + rs * 16 + q * 4;
#pragma unroll
            for (int i = 0; i < 4; ++i)
                As[rowb + i][col] = f2bf(acc[rs][tt][i]);
        }
    __syncthreads();
#pragma unroll
    for (int it = 0; it < 4; ++it) {
        int idx = it * 256 + t;
        int row = idx >> 4, seg = idx & 15;
        int r = base + row;
        if (r < n)
            ((uint4*)(H + (size_t)r * DIM))[seg] = *((const uint4*)&As[row][seg * 8]);
    }
}

// ---------------- fused agg + GEMM (layers 1,2) ----------------
// Each block aggregates its 64 A-rows (gather Hp + self + bias + ELU) into LDS,
// then computes H_out = A @ W via MFMA. Eliminates the AGG intermediate.
__global__ __launch_bounds__(256) void k_fgemm(const unsigned short* __restrict__ Hp,
                                               const int* __restrict__ offsets,
                                               const int2* __restrict__ adjw,
                                               const float* __restrict__ dinv,
                                               const float* __restrict__ b,
                                               const unsigned short* __restrict__ Wp,
                                               unsigned short* __restrict__ Ho, int n) {
    __shared__ __align__(16) unsigned short As[64][136];
    const int t = threadIdx.x;
    const int wid = t >> 6, lane = t & 63;
    const int wy = wid & 1, wx = wid >> 1;
    const int base = blockIdx.x * 64;

    short8 Bf[4][4];
    {
        const short8* wp8 = (const short8*)Wp;
#pragma unroll
        for (int tt = 0; tt < 4; ++tt)
#pragma unroll
            for (int kk = 0; kk < 4; ++kk)
                Bf[tt][kk] = wp8[(((wx * 4 + tt) * 4 + kk) * 64) + lane];
    }

    // --- aggregation phase: wave handles rows wid*16 .. wid*16+15 ---
    const float2 bb = ((const float2*)b)[lane];
    for (int i = 0; i < 16; ++i) {
        const int row = wid * 16 + i;
        const int c = base + row;
        float ax = 0.f, ay = 0.f;
        if (c < n) {
            float s = dinv[c];
            s = s * s;
            unsigned int hv = *(const unsigned int*)(Hp + (size_t)c * DIM + lane * 2);
            ax = bb.x + bflo(hv) * s;
            ay = bb.y + bfhi(hv) * s;
            int j = offsets[c];
            const int end = offsets[c + 1];
            for (; j + 3 < end; j += 4) {
                int2 e0 = adjw[j], e1 = adjw[j + 1], e2 = adjw[j + 2], e3 = adjw[j + 3];
                unsigned int v0 = *(const unsigned int*)(Hp + (size_t)e0.x * DIM + lane * 2);
                unsigned int v1 = *(const unsigned int*)(Hp + (size_t)e1.x * DIM + lane * 2);
                unsigned int v2 = *(const unsigned int*)(Hp + (size_t)e2.x * DIM + lane * 2);
                unsigned int v3 = *(const unsigned int*)(Hp + (size_t)e3.x * DIM + lane * 2);
                float w0 = __int_as_float(e0.y), w1 = __int_as_float(e1.y);
                float w2 = __int_as_float(e2.y), w3 = __int_as_float(e3.y);
                ax += bflo(v0) * w0 + bflo(v1) * w1 + bflo(v2) * w2 + bflo(v3) * w3;
                ay += bfhi(v0) * w0 + bfhi(v1) * w1 + bfhi(v2) * w2 + bfhi(v3) * w3;
            }
            for (; j < end; ++j) {
                int2 e = adjw[j];
                unsigned int v = *(const unsigned int*)(Hp + (size_t)e.x * DIM + lane * 2);
                float w = __int_as_float(e.y);
                ax += bflo(v) * w;
                ay += bfhi(v) * w;
            }
            ax = ax > 0.f ? ax : expf(ax) - 1.f;
            ay = ay > 0.f ? ay : expf(ay) - 1.f;
        }
        *(unsigned int*)&As[row][lane * 2] =
            (unsigned int)f2bf(ax) | ((unsigned int)f2bf(ay) << 16);
    }
    __syncthreads();

    // --- MFMA phase ---
    floatx4 acc[2][4];
#pragma unroll
    for (int rs = 0; rs < 2; ++rs)
#pragma unroll
        for (int tt = 0; tt < 4; ++tt) acc[rs][tt] = (floatx4){0.f, 0.f, 0.f, 0.f};

    const int m = lane & 15, q = lane >> 4;
#pragma unroll
    for (int rs = 0; rs < 2; ++rs) {
        const int rbase = wy * 32 + rs * 16 + m;
        short8 Af[4];
#pragma unroll
        for (int kk = 0; kk < 4; ++kk)
            Af[kk] = *((const short8*)&As[rbase][kk * 32 + q * 8]);
#pragma unroll
        for (int kk = 0; kk < 4; ++kk)
#pragma unroll
            for (int tt = 0; tt < 4; ++tt)
                acc[rs][tt] = __builtin_amdgcn_mfma_f32_16x16x32_bf16(Af[kk], Bf[tt][kk],
                                                                     acc[rs][tt], 0, 0, 0);
    }
    __syncthreads();

#pragma unroll
    for (int rs = 0; rs < 2; ++rs)
#pragma unroll
        for (int tt = 0; tt < 4; ++tt) {
            const int col = wx * 64 + tt * 16 + m;
            const int rowb = wy * 32 + rs * 16 + q * 4;
#pragma unroll
            for (int i = 0; i < 4; ++i)
                As[rowb + i][col] = f2bf(acc[rs][tt][i]);
        }
    __syncthreads();
#pragma unroll
    for (int it = 0; it < 4; ++it) {
        int idx = it * 256 + t;
        int row = idx >> 4, seg = idx & 15;
        int r = base + row;
        if (r < n)
            ((uint4*)(Ho + (size_t)r * DIM))[seg] = *((const uint4*)&As[row][seg * 8]);
    }
}

// ---------------- final agg + pool (layer 2 epilogue) ----------------
__global__ __launch_bounds__(256) void k_aggpool(const unsigned short* __restrict__ H,
                                                 const int* __restrict__ offsets,
                                                 const int2* __restrict__ adjw,
                                                 const float* __restrict__ dinv,
                                                 const float* __restrict__ b,
                                                 float* __restrict__ partials, int n) {
    const int lane = threadIdx.x & 63;
    const int wib = threadIdx.x >> 6;
    const int wid0 = (blockIdx.x * blockDim.x + threadIdx.x) >> 6;
    const int nw = (gridDim.x * blockDim.x) >> 6;
    const float2 bb = ((const float2*)b)[lane];
    float pax = 0.f, pay = 0.f;

    for (int c = wid0; c < n; c += nw) {
        float s = dinv[c];
        s = s * s;
        unsigned int hv = *(const unsigned int*)(H + (size_t)c * DIM + lane * 2);
        float ax = bb.x + bflo(hv) * s;
        float ay = bb.y + bfhi(hv) * s;
        int j = offsets[c];
        const int end = offsets[c + 1];
        for (; j + 3 < end; j += 4) {
            int2 e0 = adjw[j], e1 = adjw[j + 1], e2 = adjw[j + 2], e3 = adjw[j + 3];
            unsigned int v0 = *(const unsigned int*)(H + (size_t)e0.x * DIM + lane * 2);
            unsigned int v1 = *(const unsigned int*)(H + (size_t)e1.x * DIM + lane * 2);
            unsigned int v2 = *(const unsigned int*)(H + (size_t)e2.x * DIM + lane * 2);
            unsigned int v3 = *(const unsigned int*)(H + (size_t)e3.x * DIM + lane * 2);
            float w0 = __int_as_float(e0.y), w1 = __int_as_float(e1.y);
            float w2 = __int_as_float(e2.y), w3 = __int_as_float(e3.y);
            ax += bflo(v0) * w0 + bflo(v1) * w1 + bflo(v2) * w2 + bflo(v3) * w3;
            ay += bfhi(v0) * w0 + bfhi(v1) * w1 + bfhi(v2) * w2 + bfhi(v3) * w3;
        }
        for (; j < end; ++j) {
            int2 e = adjw[j];
            unsigned int v = *(const unsigned int*)(H + (size_t)e.x * DIM + lane * 2);
            float w = __int_as_float(e.y);
            ax += bflo(v) * w;
            ay += bfhi(v) * w;
        }
        ax = ax > 0.f ? ax : expf(ax) - 1.f;
        ay = ay > 0.f ? ay : expf(ay) - 1.f;
        pax += ax;
        pay += ay;
    }

    __shared__ float ps[4][DIM];
    ps[wib][lane * 2] = pax;
    ps[wib][lane * 2 + 1] = pay;
    __syncthreads();
    const int t = threadIdx.x;
    if (t < DIM) {
        float v = ps[0][t] + ps[1][t] + ps[2][t] + ps[3][t];
        partials[blockIdx.x * DIM + t] = v;
    }
}

__global__ void k_pool2(const float* __restrict__ partials, float* __restrict__ pooled) {
    const int d = blockIdx.x;           // 128 blocks, one per dim
    float acc = 0.f;
    for (int bk = threadIdx.x; bk < PBLK; bk += 64)
        acc += partials[bk * DIM + d];
#pragma unroll
    for (int off = 32; off; off >>= 1) acc += __shfl_down(acc, off, 64);
    if (threadIdx.x == 0) pooled[d] = acc;
}

__global__ void k_final(const float* __restrict__ pooled, const float* __restrict__ lw,
                        const float* __restrict__ lb, float* __restrict__ out) {
    int o = threadIdx.x;
    if (o < 24) {
        float acc = 0.f;
#pragma unroll 8
        for (int k = 0; k < DIM; ++k) acc += pooled[k] * lw[k * 24 + o];
        out[o] = acc * (1.0f / (float)NN) + lb[o];
    }
}

extern "C" void kernel_launch(void* const* d_in, const int* in_sizes, int n_in,
                              void* d_out, int out_size, void* d_ws, size_t ws_size,
                              hipStream_t stream) {
    const float* x  = (const float*)d_in[0];
    const int*   ei = (const int*)d_in[1];
    const float* W0 = (const float*)d_in[2];
    const float* b0 = (const float*)d_in[3];
    const float* W1 = (const float*)d_in[4];
    const float* b1 = (const float*)d_in[5];
    const float* W2 = (const float*)d_in[6];
    const float* b2 = (const float*)d_in[7];
    const float* lw = (const float*)d_in[8];
    const float* lb = (const float*)d_in[9];
    float* out = (float*)d_out;

    const int N = NN, E = NE;
    const int* rows = ei;        // sources (gather)
    const int* cols = ei + E;    // targets (aggregate)

    char* ws = (char*)d_ws;
    unsigned short* Ha  = (unsigned short*)ws;                      // 25,600,000 B
    unsigned short* Hb  = (unsigned short*)(ws + 25600000);         // 25,600,000 B
    float* dinv    = (float*)(ws + 51200000);                       // 400,000 B
    float* pooled  = (float*)(ws + 51600000);                       // 512 B
    int*   offsets = (int*)(ws + 51600512);                         // 400,128 B (N+1)
    int*   cursor  = (int*)(ws + 52000640);                         // 400,000 B
    int*   segsum  = (int*)(ws + 52400640);                         // 512 B
    int2*  adjw    = (int2*)(ws + 52401152);                        // 4,800,000 B
    unsigned short* Wp0 = (unsigned short*)(ws + 57201152);         // 32,768 B each
    unsigned short* Wp1 = Wp0 + 16384;
    unsigned short* Wp2 = Wp1 + 16384;
    float* partials = (float*)(ws + 57299456);                      // 1,048,576 B

    // ---- CSR build + W packing ----
    k_zero<<<(N + 256) / 256, 256, 0, stream>>>(offsets, N + 1);
    k_count<<<(E + 255) / 256, 256, 0, stream>>>(cols, offsets, E);
    k_rsqrt<<<(N + 255) / 256, 256, 0, stream>>>(offsets, dinv, N);
    k_scan1<<<NSEG, 256, 0, stream>>>(offsets, segsum, N);
    k_scan2<<<1, 64, 0, stream>>>(segsum, offsets, N);
    k_scan3<<<NSEG, 256, 0, stream>>>(offsets, segsum, cursor, N);
    k_fill<<<(E + 255) / 256, 256, 0, stream>>>(rows, cols, dinv, cursor, adjw, E);
    k_wpack<<<64, 256, 0, stream>>>(W0, Wp0);
    k_wpack<<<64, 256, 0, stream>>>(W1, Wp1);
    k_wpack<<<64, 256, 0, stream>>>(W2, Wp2);

    const int gemm_grid = (N + 63) / 64;

    // layer 0: H0 = bf16(x) @ W0
    k_gemm0<<<gemm_grid, 256, 0, stream>>>(x, Wp0, Ha, N);
    // layer 1: H1 = (elu(agg(H0)+b0)) @ W1   [agg fused into GEMM]
    k_fgemm<<<gemm_grid, 256, 0, stream>>>(Ha, offsets, adjw, dinv, b0, Wp1, Hb, N);
    // layer 2: H2 = (elu(agg(H1)+b1)) @ W2
    k_fgemm<<<gemm_grid, 256, 0, stream>>>(Hb, offsets, adjw, dinv, b1, Wp2, Ha, N);
    // epilogue: pooled = sum_c elu(agg(H2)+b2)
    k_aggpool<<<PBLK, 256, 0, stream>>>(Ha, offsets, adjw, dinv, b2, partials, N);

    k_pool2<<<DIM, 64, 0, stream>>>(partials, pooled);
    k_final<<<1, 64, 0, stream>>>(pooled, lw, lb, out);
}

// Round 6
// 328.850 us; speedup vs baseline: 1.2412x; 1.2412x over previous
//
#include <hip/hip_runtime.h>
#include <math.h>

#define NN 100000
#define NE 600000
#define DIM 128
#define SEG 1024
#define NSEG 98   // ceil(100000/1024)
#define PBLK 2048 // pooled-agg grid

typedef __attribute__((ext_vector_type(8))) short short8;
typedef __attribute__((ext_vector_type(4))) float floatx4;

// bf16 helpers (RNE)
static __device__ __forceinline__ unsigned short f2bf(float f) {
    union { float f; unsigned u; } v; v.f = f;
    unsigned r = v.u + 0x7fffu + ((v.u >> 16) & 1u);
    return (unsigned short)(r >> 16);
}
static __device__ __forceinline__ float bflo(unsigned int p) {
    union { unsigned u; float f; } v; v.u = p << 16; return v.f;
}
static __device__ __forceinline__ float bfhi(unsigned int p) {
    union { unsigned u; float f; } v; v.u = p & 0xffff0000u; return v.f;
}

// ---------------- CSR build ----------------
__global__ void k_zero(int* __restrict__ counts, int n1) {
    int i = blockIdx.x * blockDim.x + threadIdx.x;
    if (i < n1) counts[i] = 0;
}

__global__ void k_count(const int* __restrict__ col, int* __restrict__ counts, int E) {
    int i = blockIdx.x * blockDim.x + threadIdx.x;
    if (i < E) atomicAdd(&counts[col[i]], 1);
}

// scan phase 1 + fused dinv = rsqrt(count+1)
__global__ __launch_bounds__(256) void k_scan1(int* __restrict__ data, int* __restrict__ segsum,
                                               float* __restrict__ dinv, int n) {
    __shared__ int s[256];
    const int t = threadIdx.x;
    const int base = blockIdx.x * SEG + t * 4;
    int v[4];
#pragma unroll
    for (int i = 0; i < 4; ++i) v[i] = (base + i < n) ? data[base + i] : 0;
#pragma unroll
    for (int i = 0; i < 4; ++i)
        if (base + i < n) dinv[base + i] = rsqrtf((float)v[i] + 1.0f);
    int tsum = v[0] + v[1] + v[2] + v[3];
    s[t] = tsum;
    __syncthreads();
    for (int off = 1; off < 256; off <<= 1) {
        int x = (t >= off) ? s[t - off] : 0;
        __syncthreads();
        s[t] += x;
        __syncthreads();
    }
    int run = s[t] - tsum;
#pragma unroll
    for (int i = 0; i < 4; ++i) {
        if (base + i < n) data[base + i] = run;
        run += v[i];
    }
    if (t == 255) segsum[blockIdx.x] = s[255];
}

__global__ void k_scan2(int* __restrict__ segsum, int* __restrict__ offsets, int n) {
    if (threadIdx.x == 0 && blockIdx.x == 0) {
        int run = 0;
        for (int i = 0; i < NSEG; ++i) { int t = segsum[i]; segsum[i] = run; run += t; }
        offsets[n] = run;
    }
}

__global__ __launch_bounds__(256) void k_scan3(int* __restrict__ offsets, const int* __restrict__ segsum,
                                               int* __restrict__ cursor, int n) {
    const int base = blockIdx.x * SEG + threadIdx.x * 4;
    const int so = segsum[blockIdx.x];
#pragma unroll
    for (int i = 0; i < 4; ++i) {
        if (base + i < n) {
            int o = offsets[base + i] + so;
            offsets[base + i] = o;
            cursor[base + i] = o;
        }
    }
}

__global__ void k_fill(const int* __restrict__ rows, const int* __restrict__ cols,
                       const float* __restrict__ dinv, int* __restrict__ cursor,
                       int2* __restrict__ adjw, int E) {
    int e = blockIdx.x * blockDim.x + threadIdx.x;
    if (e < E) {
        int r = rows[e];
        int c = cols[e];
        int pos = atomicAdd(&cursor[c], 1);
        adjw[pos] = make_int2(r, __float_as_int(dinv[r] * dinv[c]));
    }
}

// ---------------- W pack (all 3 layers in one launch) ----------------
__global__ void k_wpack3(const float* __restrict__ W0, const float* __restrict__ W1,
                         const float* __restrict__ W2, unsigned short* __restrict__ Wp) {
    const int which = blockIdx.x >> 6;
    const float* W = which == 0 ? W0 : (which == 1 ? W1 : W2);
    unsigned short* dst = Wp + which * 16384;
    int e = (blockIdx.x & 63) * 256 + threadIdx.x;   // 0..16383
    int j  = e & 7;
    int L  = (e >> 3) & 63;
    int kk = (e >> 9) & 3;
    int ct = e >> 11;
    int k = kk * 32 + (L >> 4) * 8 + j;
    int c = ct * 16 + (L & 15);
    dst[e] = f2bf(W[k * DIM + c]);
}

// ---------------- MFMA GEMM: H(bf16) = A @ W ----------------
template <bool A_IS_F32>
__global__ __launch_bounds__(256) void k_gemm(const void* __restrict__ Ain,
                                              const unsigned short* __restrict__ Wp,
                                              unsigned short* __restrict__ H, int n) {
    __shared__ __align__(16) unsigned short As[64][136];
    const int t = threadIdx.x;
    const int wid = t >> 6, lane = t & 63;
    const int wy = wid & 1, wx = wid >> 1;
    const int base = blockIdx.x * 64;

    short8 Bf[4][4];
    {
        const short8* wp8 = (const short8*)Wp;
#pragma unroll
        for (int tt = 0; tt < 4; ++tt)
#pragma unroll
            for (int kk = 0; kk < 4; ++kk)
                Bf[tt][kk] = wp8[(((wx * 4 + tt) * 4 + kk) * 64) + lane];
    }

    if constexpr (A_IS_F32) {
        const float* A = (const float*)Ain;
#pragma unroll
        for (int it = 0; it < 8; ++it) {
            int idx = it * 256 + t;
            int row = idx >> 5, seg = idx & 31;
            int r = base + row;
            float4 v = make_float4(0.f, 0.f, 0.f, 0.f);
            if (r < n) v = ((const float4*)(A + (size_t)r * DIM))[seg];
            ushort4 o;
            o.x = f2bf(v.x); o.y = f2bf(v.y); o.z = f2bf(v.z); o.w = f2bf(v.w);
            *((ushort4*)&As[row][seg * 4]) = o;
        }
    } else {
        const unsigned short* A = (const unsigned short*)Ain;
#pragma unroll
        for (int it = 0; it < 4; ++it) {
            int idx = it * 256 + t;
            int row = idx >> 4, seg = idx & 15;
            int r = base + row;
            uint4 v = make_uint4(0, 0, 0, 0);
            if (r < n) v = ((const uint4*)(A + (size_t)r * DIM))[seg];
            *((uint4*)&As[row][seg * 8]) = v;
        }
    }
    __syncthreads();

    floatx4 acc[2][4];
#pragma unroll
    for (int rs = 0; rs < 2; ++rs)
#pragma unroll
        for (int tt = 0; tt < 4; ++tt) acc[rs][tt] = (floatx4){0.f, 0.f, 0.f, 0.f};

    const int m = lane & 15, q = lane >> 4;
#pragma unroll
    for (int rs = 0; rs < 2; ++rs) {
        const int rbase = wy * 32 + rs * 16 + m;
        short8 Af[4];
#pragma unroll
        for (int kk = 0; kk < 4; ++kk)
            Af[kk] = *((const short8*)&As[rbase][kk * 32 + q * 8]);
#pragma unroll
        for (int kk = 0; kk < 4; ++kk)
#pragma unroll
            for (int tt = 0; tt < 4; ++tt)
                acc[rs][tt] = __builtin_amdgcn_mfma_f32_16x16x32_bf16(Af[kk], Bf[tt][kk],
                                                                     acc[rs][tt], 0, 0, 0);
    }
    __syncthreads();

#pragma unroll
    for (int rs = 0; rs < 2; ++rs)
#pragma unroll
        for (int tt = 0; tt < 4; ++tt) {
            const int col = wx * 64 + tt * 16 + m;
            const int rowb = wy * 32 + rs * 16 + q * 4;
#pragma unroll
            for (int i = 0; i < 4; ++i)
                As[rowb + i][col] = f2bf(acc[rs][tt][i]);
        }
    __syncthreads();
#pragma unroll
    for (int it = 0; it < 4; ++it) {
        int idx = it * 256 + t;
        int row = idx >> 4, seg = idx & 15;
        int r = base + row;
        if (r < n)
            ((uint4*)(H + (size_t)r * DIM))[seg] = *((const uint4*)&As[row][seg * 8]);
    }
}

// ---------------- half-wave-per-node CSR aggregation (self + bias + ELU) ----------------
// lanes 0-31 -> node 2p, lanes 32-63 -> node 2p+1; each lane covers 4 dims (uint2).
// 2 independent edge streams per wave x unroll-4 = 8 outstanding row gathers.
__global__ __launch_bounds__(256) void k_agg2(const unsigned short* __restrict__ H,
                                              const int* __restrict__ offsets,
                                              const int2* __restrict__ adjw,
                                              const float* __restrict__ dinv,
                                              const float* __restrict__ b,
                                              unsigned short* __restrict__ AGG, int n) {
    const int lane = threadIdx.x & 63;
    const int hw = lane >> 5, hl = lane & 31;
    const int p = (blockIdx.x * blockDim.x + threadIdx.x) >> 6;
    const int c = p * 2 + hw;
    if (c >= n) return;
    const float4 bb = ((const float4*)b)[hl];
    float s = dinv[c];
    s = s * s;
    uint2 hv = *(const uint2*)(H + (size_t)c * DIM + hl * 4);
    float a0 = bb.x + bflo(hv.x) * s;
    float a1 = bb.y + bfhi(hv.x) * s;
    float a2 = bb.z + bflo(hv.y) * s;
    float a3 = bb.w + bfhi(hv.y) * s;
    int j = offsets[c];
    const int end = offsets[c + 1];
    for (; j + 3 < end; j += 4) {
        int2 e0 = adjw[j], e1 = adjw[j + 1], e2 = adjw[j + 2], e3 = adjw[j + 3];
        uint2 v0 = *(const uint2*)(H + (size_t)e0.x * DIM + hl * 4);
        uint2 v1 = *(const uint2*)(H + (size_t)e1.x * DIM + hl * 4);
        uint2 v2 = *(const uint2*)(H + (size_t)e2.x * DIM + hl * 4);
        uint2 v3 = *(const uint2*)(H + (size_t)e3.x * DIM + hl * 4);
        float w0 = __int_as_float(e0.y), w1 = __int_as_float(e1.y);
        float w2 = __int_as_float(e2.y), w3 = __int_as_float(e3.y);
        a0 += bflo(v0.x) * w0 + bflo(v1.x) * w1 + bflo(v2.x) * w2 + bflo(v3.x) * w3;
        a1 += bfhi(v0.x) * w0 + bfhi(v1.x) * w1 + bfhi(v2.x) * w2 + bfhi(v3.x) * w3;
        a2 += bflo(v0.y) * w0 + bflo(v1.y) * w1 + bflo(v2.y) * w2 + bflo(v3.y) * w3;
        a3 += bfhi(v0.y) * w0 + bfhi(v1.y) * w1 + bfhi(v2.y) * w2 + bfhi(v3.y) * w3;
    }
    for (; j < end; ++j) {
        int2 e = adjw[j];
        uint2 v = *(const uint2*)(H + (size_t)e.x * DIM + hl * 4);
        float w = __int_as_float(e.y);
        a0 += bflo(v.x) * w;
        a1 += bfhi(v.x) * w;
        a2 += bflo(v.y) * w;
        a3 += bfhi(v.y) * w;
    }
    a0 = a0 > 0.f ? a0 : expf(a0) - 1.f;
    a1 = a1 > 0.f ? a1 : expf(a1) - 1.f;
    a2 = a2 > 0.f ? a2 : expf(a2) - 1.f;
    a3 = a3 > 0.f ? a3 : expf(a3) - 1.f;
    uint2 outv;
    outv.x = (unsigned int)f2bf(a0) | ((unsigned int)f2bf(a1) << 16);
    outv.y = (unsigned int)f2bf(a2) | ((unsigned int)f2bf(a3) << 16);
    *(uint2*)(AGG + (size_t)c * DIM + hl * 4) = outv;
}

// ---------------- half-wave agg + pooling (layer 2 epilogue) ----------------
__global__ __launch_bounds__(256) void k_aggpool2(const unsigned short* __restrict__ H,
                                                  const int* __restrict__ offsets,
                                                  const int2* __restrict__ adjw,
                                                  const float* __restrict__ dinv,
                                                  const float* __restrict__ b,
                                                  float* __restrict__ partials, int n) {
    const int lane = threadIdx.x & 63;
    const int hw = lane >> 5, hl = lane & 31;
    const int wib = threadIdx.x >> 6;
    int p = (blockIdx.x * blockDim.x + threadIdx.x) >> 6;
    const int np = (gridDim.x * blockDim.x) >> 6;
    const int npair = (n + 1) >> 1;
    const float4 bb = ((const float4*)b)[hl];
    float p0 = 0.f, p1 = 0.f, p2 = 0.f, p3 = 0.f;

    for (; p < npair; p += np) {
        const int c = p * 2 + hw;
        if (c >= n) continue;
        float s = dinv[c];
        s = s * s;
        uint2 hv = *(const uint2*)(H + (size_t)c * DIM + hl * 4);
        float a0 = bb.x + bflo(hv.x) * s;
        float a1 = bb.y + bfhi(hv.x) * s;
        float a2 = bb.z + bflo(hv.y) * s;
        float a3 = bb.w + bfhi(hv.y) * s;
        int j = offsets[c];
        const int end = offsets[c + 1];
        for (; j + 3 < end; j += 4) {
            int2 e0 = adjw[j], e1 = adjw[j + 1], e2 = adjw[j + 2], e3 = adjw[j + 3];
            uint2 v0 = *(const uint2*)(H + (size_t)e0.x * DIM + hl * 4);
            uint2 v1 = *(const uint2*)(H + (size_t)e1.x * DIM + hl * 4);
            uint2 v2 = *(const uint2*)(H + (size_t)e2.x * DIM + hl * 4);
            uint2 v3 = *(const uint2*)(H + (size_t)e3.x * DIM + hl * 4);
            float w0 = __int_as_float(e0.y), w1 = __int_as_float(e1.y);
            float w2 = __int_as_float(e2.y), w3 = __int_as_float(e3.y);
            a0 += bflo(v0.x) * w0 + bflo(v1.x) * w1 + bflo(v2.x) * w2 + bflo(v3.x) * w3;
            a1 += bfhi(v0.x) * w0 + bfhi(v1.x) * w1 + bfhi(v2.x) * w2 + bfhi(v3.x) * w3;
            a2 += bflo(v0.y) * w0 + bflo(v1.y) * w1 + bflo(v2.y) * w2 + bflo(v3.y) * w3;
            a3 += bfhi(v0.y) * w0 + bfhi(v1.y) * w1 + bfhi(v2.y) * w2 + bfhi(v3.y) * w3;
        }
        for (; j < end; ++j) {
            int2 e = adjw[j];
            uint2 v = *(const uint2*)(H + (size_t)e.x * DIM + hl * 4);
            float w = __int_as_float(e.y);
            a0 += bflo(v.x) * w;
            a1 += bfhi(v.x) * w;
            a2 += bflo(v.y) * w;
            a3 += bfhi(v.y) * w;
        }
        p0 += a0 > 0.f ? a0 : expf(a0) - 1.f;
        p1 += a1 > 0.f ? a1 : expf(a1) - 1.f;
        p2 += a2 > 0.f ? a2 : expf(a2) - 1.f;
        p3 += a3 > 0.f ? a3 : expf(a3) - 1.f;
    }

    __shared__ float ps[8][DIM];
    float4 pv = make_float4(p0, p1, p2, p3);
    *(float4*)&ps[wib * 2 + hw][hl * 4] = pv;
    __syncthreads();
    const int t = threadIdx.x;
    if (t < DIM) {
        float v = 0.f;
#pragma unroll
        for (int w = 0; w < 8; ++w) v += ps[w][t];
        partials[blockIdx.x * DIM + t] = v;
    }
}

__global__ void k_pool2(const float* __restrict__ partials, float* __restrict__ pooled) {
    const int d = blockIdx.x;           // 128 blocks, one per dim
    float acc = 0.f;
    for (int bk = threadIdx.x; bk < PBLK; bk += 64)
        acc += partials[bk * DIM + d];
#pragma unroll
    for (int off = 32; off; off >>= 1) acc += __shfl_down(acc, off, 64);
    if (threadIdx.x == 0) pooled[d] = acc;
}

__global__ void k_final(const float* __restrict__ pooled, const float* __restrict__ lw,
                        const float* __restrict__ lb, float* __restrict__ out) {
    int o = threadIdx.x;
    if (o < 24) {
        float acc = 0.f;
#pragma unroll 8
        for (int k = 0; k < DIM; ++k) acc += pooled[k] * lw[k * 24 + o];
        out[o] = acc * (1.0f / (float)NN) + lb[o];
    }
}

extern "C" void kernel_launch(void* const* d_in, const int* in_sizes, int n_in,
                              void* d_out, int out_size, void* d_ws, size_t ws_size,
                              hipStream_t stream) {
    const float* x  = (const float*)d_in[0];
    const int*   ei = (const int*)d_in[1];
    const float* W0 = (const float*)d_in[2];
    const float* b0 = (const float*)d_in[3];
    const float* W1 = (const float*)d_in[4];
    const float* b1 = (const float*)d_in[5];
    const float* W2 = (const float*)d_in[6];
    const float* b2 = (const float*)d_in[7];
    const float* lw = (const float*)d_in[8];
    const float* lb = (const float*)d_in[9];
    float* out = (float*)d_out;

    const int N = NN, E = NE;
    const int* rows = ei;        // sources (gather)
    const int* cols = ei + E;    // targets (aggregate)

    char* ws = (char*)d_ws;
    unsigned short* H   = (unsigned short*)ws;                      // 25,600,000 B
    unsigned short* AGG = (unsigned short*)(ws + 25600000);         // 25,600,000 B
    float* dinv    = (float*)(ws + 51200000);                       // 400,000 B
    float* pooled  = (float*)(ws + 51600000);                       // 512 B
    int*   offsets = (int*)(ws + 51600512);                         // 400,128 B (N+1)
    int*   cursor  = (int*)(ws + 52000640);                         // 400,000 B
    int*   segsum  = (int*)(ws + 52400640);                         // 512 B
    int2*  adjw    = (int2*)(ws + 52401152);                        // 4,800,000 B
    unsigned short* Wp = (unsigned short*)(ws + 57201152);          // 3 x 32,768 B
    float* partials = (float*)(ws + 57299456);                      // 1,048,576 B

    // ---- CSR build + W packing ----
    k_zero<<<(N + 256) / 256, 256, 0, stream>>>(offsets, N + 1);
    k_count<<<(E + 255) / 256, 256, 0, stream>>>(cols, offsets, E);
    k_scan1<<<NSEG, 256, 0, stream>>>(offsets, segsum, dinv, N);
    k_scan2<<<1, 64, 0, stream>>>(segsum, offsets, N);
    k_scan3<<<NSEG, 256, 0, stream>>>(offsets, segsum, cursor, N);
    k_fill<<<(E + 255) / 256, 256, 0, stream>>>(rows, cols, dinv, cursor, adjw, E);
    k_wpack3<<<192, 256, 0, stream>>>(W0, W1, W2, Wp);

    const int gemm_grid = (N + 63) / 64;
    const int agg_grid = (((N + 1) / 2) * 64 + 255) / 256;

    // layer 0
    k_gemm<true><<<gemm_grid, 256, 0, stream>>>((const void*)x, Wp, H, N);
    k_agg2<<<agg_grid, 256, 0, stream>>>(H, offsets, adjw, dinv, b0, AGG, N);
    // layer 1
    k_gemm<false><<<gemm_grid, 256, 0, stream>>>((const void*)AGG, Wp + 16384, H, N);
    k_agg2<<<agg_grid, 256, 0, stream>>>(H, offsets, adjw, dinv, b1, AGG, N);
    // layer 2 (pooling fused)
    k_gemm<false><<<gemm_grid, 256, 0, stream>>>((const void*)AGG, Wp + 32768, H, N);
    k_aggpool2<<<PBLK, 256, 0, stream>>>(H, offsets, adjw, dinv, b2, partials, N);

    k_pool2<<<DIM, 64, 0, stream>>>(partials, pooled);
    k_final<<<1, 64, 0, stream>>>(pooled, lw, lb, out);
}